// Round 4
// baseline (89268.488 us; speedup 1.0000x reference)
//
#include <hip/hip_runtime.h>
#include <math.h>

typedef float v4 __attribute__((ext_vector_type(4)));

#define NB 256
#define LATD 128
#define UPS 64
#define H 512
#define V 25
#define TS 500
#define LGS 32
#define NBLK 256
#define NGRP 16
#define GSZ (NBLK / NGRP)

// relaxed agent-scope (MALL / Infinity-Cache coherent) access — no cache invalidates
#define AL(p)    __hip_atomic_load((p), __ATOMIC_RELAXED, __HIP_MEMORY_SCOPE_AGENT)
#define AS(p, x) __hip_atomic_store((p), (x), __ATOMIC_RELAXED, __HIP_MEMORY_SCOPE_AGENT)

// ---- float offsets in workspace ----
#define OFF_HQ      0                            // hQ[2][128][NB][4]
#define OFF_UCTXQ   (OFF_HQ + 2 * 128 * NB * 4)  // uctxQ[16][NB][4]
#define OFF_EGI     (OFF_UCTXQ + 16 * NB * 4)    // EgiT[1536][32]
#define OFF_WHHQ    (OFF_EGI + 1536 * 32)        // Whh_q[128][1536][4]
#define OFF_WCATQ   (OFF_WHHQ + 128 * 1536 * 4)  // Wcat_q[128][512][4]
#define OFF_WFOLDQ  (OFF_WCATQ + 128 * 512 * 4)  // Wfold_q[16][512][4]
#define OFF_WMQ     (OFF_WFOLDQ + 16 * 512 * 4)  // Wm_q2[128][64][4]
#define OFF_BCAT2   (OFF_WMQ + 128 * 64 * 4)     // bcat2[512]
#define OFF_LGT     (OFF_BCAT2 + 512)            // logitsT[2][32][NB]
#define OFF_BAR     (OFF_LGT + 2 * LGS * NB)     // barrier ints

__device__ __forceinline__ float dot4(v4 a, v4 b) {
    return a.x * b.x + a.y * b.y + a.z * b.z + a.w * b.w;
}

// ---------------- init kernels (plain stores; visible to k_main via dispatch boundary) ----------------

__global__ void k_init_egi(const float* __restrict__ embed, const float* __restrict__ W_ih,
                           const float* __restrict__ b_ih, float* __restrict__ EgiT) {
    int idx = blockIdx.x * 256 + threadIdx.x;
    if (idx >= V * 3 * H) return;
    int v = idx % V, n = idx / V;
    const float* e = embed + (size_t)v * H;
    const float* wr = W_ih + (size_t)n * H;
    float acc = b_ih[n];
    for (int k = 0; k < H; ++k) acc += e[k] * wr[k];
    EgiT[n * 32 + v] = acc;
}

__global__ void k_init_h0(const float* __restrict__ latent, const float* __restrict__ W_hid,
                          const float* __restrict__ b_hid, float* __restrict__ hQ) {
    int b = blockIdx.x, j = threadIdx.x;
    const float* l = latent + (size_t)b * LATD;
    const float* wr = W_hid + (size_t)j * LATD;
    float acc = b_hid[j];
    for (int k = 0; k < LATD; ++k) acc += l[k] * wr[k];
    hQ[((j >> 2) * NB + b) * 4 + (j & 3)] = acc;
}

__global__ void k_pack_whh(const float* __restrict__ W_hh, float* __restrict__ Whh_q) {
    int idx = blockIdx.x * 256 + threadIdx.x;
    if (idx >= 1536 * 128) return;
    int k4 = idx & 127, row = idx >> 7;
    v4 val = *(const v4*)(W_hh + (size_t)row * H + k4 * 4);
    *(v4*)(Whh_q + ((size_t)k4 * 1536 + row) * 4) = val;
}

__global__ void k_pack_wcat(const float* __restrict__ W_cat, float* __restrict__ Wcat_q) {
    int idx = blockIdx.x * 256 + threadIdx.x;
    if (idx >= 512 * 128) return;
    int k4 = idx & 127, row = idx >> 7;
    v4 val = *(const v4*)(W_cat + (size_t)row * (2 * H) + k4 * 4);
    *(v4*)(Wcat_q + ((size_t)k4 * 512 + row) * 4) = val;
}

__global__ void k_init_fold(const float* __restrict__ W_cat, const float* __restrict__ W_mem,
                            float* __restrict__ Wfold_q) {
    int idx = blockIdx.x * 256 + threadIdx.x;
    if (idx >= H * UPS) return;
    int u = idx & 63, j = idx >> 6;
    float acc = 0.f;
    for (int k = 0; k < H; ++k)
        acc += W_cat[(size_t)j * (2 * H) + H + k] * W_mem[(size_t)k * UPS + u];
    Wfold_q[((u >> 2) * 512 + j) * 4 + (u & 3)] = acc;
}

__global__ void k_init_bcat(const float* __restrict__ W_cat, const float* __restrict__ b_mem,
                            const float* __restrict__ b_cat, float* __restrict__ bcat2) {
    int j = blockIdx.x * 256 + threadIdx.x;
    if (j >= H) return;
    float acc = b_cat[j];
    for (int k = 0; k < H; ++k) acc += W_cat[(size_t)j * (2 * H) + H + k] * b_mem[k];
    bcat2[j] = acc;
}

__global__ void k_pack_wmem(const float* __restrict__ W_mem, float* __restrict__ Wm_q2) {
    int idx = blockIdx.x * 256 + threadIdx.x;
    if (idx >= 128 * 64) return;
    int u = idx & 63, k4 = idx >> 6;
    v4 val;
    val.x = W_mem[(size_t)(k4 * 4 + 0) * UPS + u];
    val.y = W_mem[(size_t)(k4 * 4 + 1) * UPS + u];
    val.z = W_mem[(size_t)(k4 * 4 + 2) * UPS + u];
    val.w = W_mem[(size_t)(k4 * 4 + 3) * UPS + u];
    *(v4*)(Wm_q2 + ((size_t)k4 * 64 + u) * 4) = val;
}

__global__ void k_init_bar(int* __restrict__ bar) {
    int i = threadIdx.x;
    if (i < NGRP * 32 + 64) bar[i] = 0;
}

// ---------------- fence-free grid barrier (no L2 invalidation) ----------------
// Producer visibility: all cross-block data uses write-through agent stores, drained
// by the vmcnt(0) __syncthreads emits before s_barrier. fetch_adds use RELEASE
// (dirty-line writeback only, no invalidate). Consumers re-read via agent loads
// (MALL-coherent), so the spin needs no ACQUIRE — L1/L2 read caches stay intact.

__device__ __forceinline__ void grid_barrier(int* bar, int epoch) {
    __syncthreads();
    asm volatile("" ::: "memory");
    if (threadIdx.x == 0) {
        int* gcnt = bar + (blockIdx.x & (NGRP - 1)) * 32;
        int* root = bar + NGRP * 32;
        int* gen  = bar + NGRP * 32 + 32;
        int a = __hip_atomic_fetch_add(gcnt, 1, __ATOMIC_RELEASE, __HIP_MEMORY_SCOPE_AGENT);
        if (a == epoch * GSZ + (GSZ - 1)) {
            int r = __hip_atomic_fetch_add(root, 1, __ATOMIC_RELEASE, __HIP_MEMORY_SCOPE_AGENT);
            if (r == epoch * NGRP + (NGRP - 1))
                __hip_atomic_store(gen, epoch + 1, __ATOMIC_RELEASE, __HIP_MEMORY_SCOPE_AGENT);
        }
        while (__hip_atomic_load(gen, __ATOMIC_RELAXED, __HIP_MEMORY_SCOPE_AGENT) <= epoch)
            __builtin_amdgcn_s_sleep(4);
    }
    asm volatile("" ::: "memory");
    __syncthreads();
}

// ---------------- persistent main kernel ----------------

__global__ __launch_bounds__(512, 4) void k_main(
    const float* __restrict__ up, const float* __restrict__ b_hh,
    const float* __restrict__ W_out, const float* __restrict__ b_out,
    float* __restrict__ out, float* __restrict__ ws)
{
    float* hQ       = ws + OFF_HQ;
    float* uctxQ    = ws + OFF_UCTXQ;
    const float* EgiT    = ws + OFF_EGI;
    const float* Whh_q   = ws + OFF_WHHQ;
    const float* Wcat_q  = ws + OFF_WCATQ;
    const float* Wfold_q = ws + OFF_WFOLDQ;
    const float* Wm_q2   = ws + OFF_WMQ;
    const float* bcat2   = ws + OFF_BCAT2;
    float* lgT      = ws + OFF_LGT;
    int*   bar      = (int*)(ws + OFF_BAR);

    const int tid = threadIdx.x;
    const int bid = blockIdx.x;
    const int lane = tid & 63, w = tid >> 6;
    const int bq = bid & 3, jb = bid >> 2;
    const int jg = lane & 7, bg = lane >> 3;
    const int b = bq * 64 + w * 8 + bg;     // P1/P3 batch index
    const int j = jb * 8 + jg;              // P1/P3 output index

    const v4* wq4  = (const v4*)Whh_q;
    const v4* wc4  = (const v4*)Wcat_q;
    const v4* wf4  = (const v4*)Wfold_q;
    const v4* wm4  = (const v4*)Wm_q2;

    __shared__ __align__(16) float s_h[512];
    __shared__ float s_part[8][64];
    __shared__ __align__(16) float s_hp[64];
    __shared__ float s_ctx[8][64];
    __shared__ float s_mw[8], s_Sw[8];

    int ep = 0;

    for (int t = 0; t < TS; ++t) {
        float* hQc = hQ + (size_t)(t & 1) * (128 * NB * 4);
        float* hQn = hQ + (size_t)((t + 1) & 1) * (128 * NB * 4);
        float* lgprev = lgT + ((t + 1) & 1) * (LGS * NB);
        float* lgcur = lgT + (t & 1) * (LGS * NB);

        // ================= P1: argmax feedback + GRU =================
        int id = 0;
        if (t > 0) {
            float best = AL(lgprev + 0 * NB + b);
            for (int v = 1; v < V; ++v) {
                float x = AL(lgprev + v * NB + b);
                if (x > best) { best = x; id = v; }
            }
        }
        if (jb == 0 && t > 0) {  // write output logits for step t-1 (this quarter)
            for (int i = tid; i < 64 * 32; i += 512) {
                int v = i & 31, bl = i >> 5;
                if (v < V) {
                    int bb = bq * 64 + bl;
                    out[((size_t)bb * V + v) * TS + (t - 1)] = AL(lgprev + v * NB + bb);
                }
            }
        }
        if (jb == 1) {  // bias-init logits accumulator (agent stores: P3 RMWs at MALL)
            for (int i = tid; i < V * 64; i += 512) {
                int v = i >> 6, bl = i & 63;
                AS(lgcur + v * NB + bq * 64 + bl, b_out[v]);
            }
        }
        {
            float ar = 0.f, az = 0.f, an = 0.f;
#pragma unroll 4
            for (int k4 = 0; k4 < 128; ++k4) {
                const float* hp = hQc + (size_t)(k4 * NB + b) * 4;
                float x0 = AL(hp + 0), x1 = AL(hp + 1), x2 = AL(hp + 2), x3 = AL(hp + 3);
                v4 wr = wq4[k4 * 1536 + j];
                v4 wz = wq4[k4 * 1536 + 512 + j];
                v4 wn = wq4[k4 * 1536 + 1024 + j];
                ar += x0 * wr.x + x1 * wr.y + x2 * wr.z + x3 * wr.w;
                az += x0 * wz.x + x1 * wz.y + x2 * wz.z + x3 * wz.w;
                an += x0 * wn.x + x1 * wn.y + x2 * wn.z + x3 * wn.w;
            }
            float gir = EgiT[(0 * H + j) * 32 + id];
            float giz = EgiT[(1 * H + j) * 32 + id];
            float gin = EgiT[(2 * H + j) * 32 + id];
            float sr = ar + b_hh[j] + gir;
            float sz = az + b_hh[H + j] + giz;
            float sn = an + b_hh[2 * H + j];
            float r = 1.f / (1.f + __expf(-sr));
            float z = 1.f / (1.f + __expf(-sz));
            float n = tanhf(gin + r * sn);
            int hidx = ((j >> 2) * NB + b) * 4 + (j & 3);
            float hold = AL(hQc + hidx);
            AS(hQn + hidx, (1.f - z) * n + z * hold);
        }
        grid_barrier(bar, ep++);

        // ================= P2: attention (flash-style, one block per b) =================
        {
            const int b2 = bid;
            // stage h_new[b2][:] into LDS once (cross-block -> agent loads)
            s_h[tid] = AL(hQn + ((size_t)(tid >> 2) * NB + b2) * 4 + (tid & 3));
            __syncthreads();
            const v4* s_h4 = (const v4*)s_h;
            {
                float a = 0.f;
#pragma unroll 4
                for (int i = 0; i < 16; ++i) {
                    int k4 = w * 16 + i;
                    v4 hv = s_h4[k4];                // LDS broadcast
                    v4 wv = wm4[k4 * 64 + lane];     // cached, coalesced
                    a += dot4(hv, wv);
                }
                s_part[w][lane] = a;
            }
            __syncthreads();
            if (w == 0) {
                float a = s_part[0][lane];
                for (int i = 1; i < 8; ++i) a += s_part[i][lane];
                s_hp[lane] = a;
            }
            __syncthreads();

            const int u0 = (lane & 7) * 8;
            const int tsub = lane >> 3;
            v4 hpA = *(const v4*)&s_hp[u0];
            v4 hpB = *(const v4*)&s_hp[u0 + 4];
            float m = -1e30f, S = 0.f;
            float cx[8] = {0.f, 0.f, 0.f, 0.f, 0.f, 0.f, 0.f, 0.f};
#pragma unroll
            for (int p = 0; p < 8; ++p) {
                int tt = p * 64 + w * 8 + tsub;
                v4 ua = {0.f, 0.f, 0.f, 0.f}, ub = {0.f, 0.f, 0.f, 0.f};
                float part = 0.f;
                if (tt < TS) {
                    const v4* ur = (const v4*)(up + ((size_t)b2 * TS + tt) * UPS + u0);
                    ua = ur[0];
                    ub = ur[1];
                    part = dot4(ua, hpA) + dot4(ub, hpB);
                }
                part += __shfl_xor(part, 1);
                part += __shfl_xor(part, 2);
                part += __shfl_xor(part, 4);
                float s = (tt < TS) ? part : -1e30f;
                float M = s;
                M = fmaxf(M, __shfl_xor(M, 8));
                M = fmaxf(M, __shfl_xor(M, 16));
                M = fmaxf(M, __shfl_xor(M, 32));
                float mn = fmaxf(m, M);
                float alpha = __expf(m - mn);
                float e = __expf(s - mn);
                float E = e;
                E += __shfl_xor(E, 8); E += __shfl_xor(E, 16); E += __shfl_xor(E, 32);
                S = S * alpha + E;
                m = mn;
#pragma unroll
                for (int i = 0; i < 4; ++i) cx[i] = cx[i] * alpha + e * ua[i];
#pragma unroll
                for (int i = 0; i < 4; ++i) cx[4 + i] = cx[4 + i] * alpha + e * ub[i];
            }
#pragma unroll
            for (int i = 0; i < 8; ++i) {
                cx[i] += __shfl_xor(cx[i], 8);
                cx[i] += __shfl_xor(cx[i], 16);
                cx[i] += __shfl_xor(cx[i], 32);
            }
            if (tsub == 0) {
#pragma unroll
                for (int i = 0; i < 8; ++i) s_ctx[w][u0 + i] = cx[i];
            }
            if (lane == 0) { s_mw[w] = m; s_Sw[w] = S; }
            __syncthreads();
            if (tid < UPS) {
                float M = s_mw[0];
                for (int i = 1; i < 8; ++i) M = fmaxf(M, s_mw[i]);
                float Sg = 0.f, c = 0.f;
                for (int i = 0; i < 8; ++i) {
                    float f = __expf(s_mw[i] - M);
                    Sg += s_Sw[i] * f;
                    c += s_ctx[i][tid] * f;
                }
                AS(uctxQ + ((size_t)(tid >> 2) * NB + b2) * 4 + (tid & 3), c / Sg);
            }
        }
        grid_barrier(bar, ep++);

        // ================= P3: concat GEMM + folded logits =================
        {
            float acc = 0.f;
#pragma unroll 4
            for (int k4 = 0; k4 < 128; ++k4) {
                const float* hp = hQn + (size_t)(k4 * NB + b) * 4;
                float x0 = AL(hp + 0), x1 = AL(hp + 1), x2 = AL(hp + 2), x3 = AL(hp + 3);
                v4 wv = wc4[k4 * 512 + j];
                acc += x0 * wv.x + x1 * wv.y + x2 * wv.z + x3 * wv.w;
            }
#pragma unroll
            for (int u4 = 0; u4 < 16; ++u4) {
                const float* cp = uctxQ + (size_t)(u4 * NB + b) * 4;
                float c0 = AL(cp + 0), c1 = AL(cp + 1), c2 = AL(cp + 2), c3 = AL(cp + 3);
                v4 wv = wf4[u4 * 512 + j];
                acc += c0 * wv.x + c1 * wv.y + c2 * wv.z + c3 * wv.w;
            }
            float c = tanhf(acc + bcat2[j]);
            for (int v = 0; v < V; ++v) {
                float p = c * W_out[(size_t)v * H + j];
                p += __shfl_xor(p, 1);
                p += __shfl_xor(p, 2);
                p += __shfl_xor(p, 4);
                if (jg == 0) atomicAdd(&lgcur[v * NB + b], p);
            }
        }
        grid_barrier(bar, ep++);
    }

    // final output write for t = TS-1
    if (jb == 0) {
        float* lgfin = lgT + ((TS - 1) & 1) * (LGS * NB);
        for (int i = tid; i < 64 * 32; i += 512) {
            int v = i & 31, bl = i >> 5;
            if (v < V) {
                int bb = bq * 64 + bl;
                out[((size_t)bb * V + v) * TS + (TS - 1)] = AL(lgfin + v * NB + bb);
            }
        }
    }
}

// ---------------- launcher ----------------

extern "C" void kernel_launch(void* const* d_in, const int* in_sizes, int n_in,
                              void* d_out, int out_size, void* d_ws, size_t ws_size,
                              hipStream_t stream) {
    const float* latent = (const float*)d_in[0];
    const float* up     = (const float*)d_in[1];
    const float* embed  = (const float*)d_in[2];
    const float* W_hid  = (const float*)d_in[3];
    const float* b_hid  = (const float*)d_in[4];
    const float* W_ih   = (const float*)d_in[5];
    const float* b_ih   = (const float*)d_in[6];
    const float* W_hh   = (const float*)d_in[7];
    const float* b_hh   = (const float*)d_in[8];
    const float* W_mem  = (const float*)d_in[9];
    const float* b_mem  = (const float*)d_in[10];
    const float* W_cat  = (const float*)d_in[11];
    const float* b_cat  = (const float*)d_in[12];
    const float* W_out  = (const float*)d_in[13];
    const float* b_out  = (const float*)d_in[14];
    float* out = (float*)d_out;
    float* ws = (float*)d_ws;

    k_init_egi<<<(V * 3 * H + 255) / 256, 256, 0, stream>>>(embed, W_ih, b_ih, ws + OFF_EGI);
    k_init_h0<<<NB, H, 0, stream>>>(latent, W_hid, b_hid, ws + OFF_HQ);
    k_pack_whh<<<(1536 * 128 + 255) / 256, 256, 0, stream>>>(W_hh, ws + OFF_WHHQ);
    k_pack_wcat<<<(512 * 128 + 255) / 256, 256, 0, stream>>>(W_cat, ws + OFF_WCATQ);
    k_init_fold<<<(H * UPS + 255) / 256, 256, 0, stream>>>(W_cat, W_mem, ws + OFF_WFOLDQ);
    k_init_bcat<<<(H + 255) / 256, 256, 0, stream>>>(W_cat, b_mem, b_cat, ws + OFF_BCAT2);
    k_pack_wmem<<<(128 * 64 + 255) / 256, 256, 0, stream>>>(W_mem, ws + OFF_WMQ);
    k_init_bar<<<1, 1024, 0, stream>>>((int*)(ws + OFF_BAR));

    k_main<<<NBLK, 512, 0, stream>>>(up, b_hh, W_out, b_out, out, ws);
}

// Round 5
// 56525.598 us; speedup vs baseline: 1.5793x; 1.5793x over previous
//
#include <hip/hip_runtime.h>
#include <math.h>

typedef float v4 __attribute__((ext_vector_type(4)));

#define NB 256
#define LATD 128
#define UPS 64
#define H 512
#define V 25
#define TS 500
#define NBLK 256
#define NGRP 16
#define GSZ (NBLK / NGRP)

// ---- float offsets in workspace ----
#define OFF_HP     0                        // hP[8][128][32][4]      (group, k4, bg, e)
#define OFF_UCTX   (OFF_HP + 131072)        // uctx[8][32][64]
#define OFF_LGF    (OFF_UCTX + 16384)       // lg_final[8][25][32]
#define OFF_LGP    (OFF_LGF + 6400)         // lgp[256 blocks][25][32]
#define OFF_EGI    (OFF_LGP + 204800)       // EgiT[1536][32]
#define OFF_WHHQ   (OFF_EGI + 49152)        // Whh_q[128][1536][4]
#define OFF_WCATQ  (OFF_WHHQ + 786432)      // Wcat_q[128][512][4]
#define OFF_WFOLDQ (OFF_WCATQ + 262144)     // Wfold_q[16][512][4]
#define OFF_WMQ    (OFF_WFOLDQ + 32768)     // Wm_q2[128][64][4]
#define OFF_BCAT2  (OFF_WMQ + 32768)        // bcat2[512]
#define OFF_BAR    (OFF_BCAT2 + 512)        // barrier ints

__device__ __forceinline__ float dot4(v4 a, v4 b) {
    return a.x * b.x + a.y * b.y + a.z * b.z + a.w * b.w;
}

// ---- MALL-coherent (system-scope flags) bulk access helpers ----
__device__ __forceinline__ float pullf(const float* p) {
    float r;
    asm volatile("global_load_dword %0, %1, off sc0 sc1" : "=v"(r) : "v"(p));
    return r;
}
__device__ __forceinline__ v4 pull4(const float* p) {
    v4 r;
    asm volatile("global_load_dwordx4 %0, %1, off sc0 sc1" : "=v"(r) : "v"(p));
    return r;
}
__device__ __forceinline__ void pushf(float* p, float x) {
    asm volatile("global_store_dword %0, %1, off sc0 sc1" :: "v"(p), "v"(x));
}
__device__ __forceinline__ void wait_pull() {
    asm volatile("s_waitcnt vmcnt(0)" ::: "memory");
    __builtin_amdgcn_sched_barrier(0);
}

// ---------------- init kernels ----------------

__global__ void k_init_egi(const float* __restrict__ embed, const float* __restrict__ W_ih,
                           const float* __restrict__ b_ih, float* __restrict__ EgiT) {
    int idx = blockIdx.x * 256 + threadIdx.x;
    if (idx >= V * 3 * H) return;
    int v = idx % V, n = idx / V;
    const float* e = embed + (size_t)v * H;
    const float* wr = W_ih + (size_t)n * H;
    float acc = b_ih[n];
    for (int k = 0; k < H; ++k) acc += e[k] * wr[k];
    EgiT[n * 32 + v] = acc;
}

__global__ void k_init_h0(const float* __restrict__ latent, const float* __restrict__ W_hid,
                          const float* __restrict__ b_hid, float* __restrict__ hP) {
    int b = blockIdx.x, j = threadIdx.x;
    const float* l = latent + (size_t)b * LATD;
    const float* wr = W_hid + (size_t)j * LATD;
    float acc = b_hid[j];
    for (int k = 0; k < LATD; ++k) acc += l[k] * wr[k];
    int x = b >> 5, bg = b & 31;
    hP[x * 16384 + ((j >> 2) * 32 + bg) * 4 + (j & 3)] = acc;
}

__global__ void k_pack_whh(const float* __restrict__ W_hh, float* __restrict__ Whh_q) {
    int idx = blockIdx.x * 256 + threadIdx.x;
    if (idx >= 1536 * 128) return;
    int k4 = idx & 127, row = idx >> 7;
    v4 val = *(const v4*)(W_hh + (size_t)row * H + k4 * 4);
    *(v4*)(Whh_q + ((size_t)k4 * 1536 + row) * 4) = val;
}

__global__ void k_pack_wcat(const float* __restrict__ W_cat, float* __restrict__ Wcat_q) {
    int idx = blockIdx.x * 256 + threadIdx.x;
    if (idx >= 512 * 128) return;
    int k4 = idx & 127, row = idx >> 7;
    v4 val = *(const v4*)(W_cat + (size_t)row * (2 * H) + k4 * 4);
    *(v4*)(Wcat_q + ((size_t)k4 * 512 + row) * 4) = val;
}

__global__ void k_init_fold(const float* __restrict__ W_cat, const float* __restrict__ W_mem,
                            float* __restrict__ Wfold_q) {
    int idx = blockIdx.x * 256 + threadIdx.x;
    if (idx >= H * UPS) return;
    int u = idx & 63, j = idx >> 6;
    float acc = 0.f;
    for (int k = 0; k < H; ++k)
        acc += W_cat[(size_t)j * (2 * H) + H + k] * W_mem[(size_t)k * UPS + u];
    Wfold_q[((u >> 2) * 512 + j) * 4 + (u & 3)] = acc;
}

__global__ void k_init_bcat(const float* __restrict__ W_cat, const float* __restrict__ b_mem,
                            const float* __restrict__ b_cat, float* __restrict__ bcat2) {
    int j = blockIdx.x * 256 + threadIdx.x;
    if (j >= H) return;
    float acc = b_cat[j];
    for (int k = 0; k < H; ++k) acc += W_cat[(size_t)j * (2 * H) + H + k] * b_mem[k];
    bcat2[j] = acc;
}

__global__ void k_pack_wmem(const float* __restrict__ W_mem, float* __restrict__ Wm_q2) {
    int idx = blockIdx.x * 256 + threadIdx.x;
    if (idx >= 128 * 64) return;
    int u = idx & 63, k4 = idx >> 6;
    v4 val;
    val.x = W_mem[(size_t)(k4 * 4 + 0) * UPS + u];
    val.y = W_mem[(size_t)(k4 * 4 + 1) * UPS + u];
    val.z = W_mem[(size_t)(k4 * 4 + 2) * UPS + u];
    val.w = W_mem[(size_t)(k4 * 4 + 3) * UPS + u];
    *(v4*)(Wm_q2 + ((size_t)k4 * 64 + u) * 4) = val;
}

__global__ void k_init_bar(int* __restrict__ bar) {
    int i = threadIdx.x;
    if (i < NGRP * 32 + 64) bar[i] = 0;
}

// ---------------- grid barrier (round-4 proven semantics + asm-store drain) ----------------

__device__ __forceinline__ void grid_barrier(int* bar, int epoch) {
    asm volatile("s_waitcnt vmcnt(0)" ::: "memory");  // drain asm pushes of this wave
    __syncthreads();
    asm volatile("" ::: "memory");
    if (threadIdx.x == 0) {
        int* gcnt = bar + (blockIdx.x & (NGRP - 1)) * 32;
        int* root = bar + NGRP * 32;
        int* gen  = bar + NGRP * 32 + 32;
        int a = __hip_atomic_fetch_add(gcnt, 1, __ATOMIC_RELEASE, __HIP_MEMORY_SCOPE_AGENT);
        if (a == epoch * GSZ + (GSZ - 1)) {
            int r = __hip_atomic_fetch_add(root, 1, __ATOMIC_RELEASE, __HIP_MEMORY_SCOPE_AGENT);
            if (r == epoch * NGRP + (NGRP - 1))
                __hip_atomic_store(gen, epoch + 1, __ATOMIC_RELEASE, __HIP_MEMORY_SCOPE_AGENT);
        }
        while (__hip_atomic_load(gen, __ATOMIC_RELAXED, __HIP_MEMORY_SCOPE_AGENT) <= epoch)
            __builtin_amdgcn_s_sleep(2);
    }
    asm volatile("" ::: "memory");
    __syncthreads();
}

// ---------------- persistent main kernel ----------------

__global__ __launch_bounds__(512, 1) void k_main(
    const float* __restrict__ up, const float* __restrict__ b_hh,
    const float* __restrict__ W_out, const float* __restrict__ b_out,
    float* __restrict__ out, float* __restrict__ ws)
{
    float* hP       = ws + OFF_HP;
    float* uctxB    = ws + OFF_UCTX;
    float* lgF      = ws + OFF_LGF;
    float* lgP      = ws + OFF_LGP;
    const float* EgiT    = ws + OFF_EGI;
    const float* Whh_q   = ws + OFF_WHHQ;
    const float* Wcat_q  = ws + OFF_WCATQ;
    const float* Wfold_q = ws + OFF_WFOLDQ;
    const float* Wm_q2   = ws + OFF_WMQ;
    const float* bcat2   = ws + OFF_BCAT2;
    int*   bar      = (int*)(ws + OFF_BAR);

    const int tid = threadIdx.x;
    const int bid = blockIdx.x;
    const int x = bid & 7;          // batch group (32 rows)
    const int m = bid >> 3;         // j-slice / role index within group
    const int bg = tid >> 4;        // [0,32) batch row within group
    const int jg = tid & 15;        // [0,16) j within slice
    const int j = m * 16 + jg;
    const int w = tid >> 6, lane = tid & 63;

    const v4* wq4 = (const v4*)Whh_q;
    const v4* wc4 = (const v4*)Wcat_q;
    const v4* wf4 = (const v4*)Wfold_q;
    const v4* wm4 = (const v4*)Wm_q2;

    float* hPx = hP + x * 16384;
    float* uctxX = uctxB + x * 2048;

    __shared__ __align__(16) float s_h[16384];     // 64 KB: h[k4][bg] v4-packed
    __shared__ float s_lgf[832];
    __shared__ float s_uctx[32 * 68];              // padded rows (bank-conflict-free)
    __shared__ float s_lgp[800];
    __shared__ __align__(16) float s_hrow[512];
    __shared__ float s_part[8][64];
    __shared__ __align__(16) float s_hp[64];
    __shared__ float s_ctx[8][64];
    __shared__ float s_mw[8], s_Sw[8];
    __shared__ float s_red[16][32];

    int ep = 0;

    // ---- pre-loop: stage h0 into LDS ----
    {
        v4 tmp[8];
#pragma unroll
        for (int i = 0; i < 8; ++i) tmp[i] = pull4(hPx + (i * 512 + tid) * 4);
        wait_pull();
        v4* sh4w = (v4*)s_h;
#pragma unroll
        for (int i = 0; i < 8; ++i) sh4w[i * 512 + tid] = tmp[i];
    }
    grid_barrier(bar, ep++);

    for (int t = 0; t < TS; ++t) {
        const v4* sh4 = (const v4*)s_h;

        // ================= P1: argmax feedback + GRU (h from LDS) =================
        if (t > 0) {
            float v0 = pullf(lgF + x * 800 + tid);
            float v1 = 0.f;
            if (tid + 512 < 800) v1 = pullf(lgF + x * 800 + tid + 512);
            wait_pull();
            s_lgf[tid] = v0;
            if (tid + 512 < 800) s_lgf[tid + 512] = v1;
        }
        __syncthreads();
        int id = 0;
        if (t > 0) {
            float best = s_lgf[bg];
            for (int v = 1; v < V; ++v) {
                float xv = s_lgf[v * 32 + bg];
                if (xv > best) { best = xv; id = v; }
            }
        }
        {
            float ar = 0.f, az = 0.f, an = 0.f;
#pragma unroll 4
            for (int k4 = 0; k4 < 128; ++k4) {
                v4 hv = sh4[k4 * 32 + bg];
                v4 wr = wq4[k4 * 1536 + j];
                v4 wz = wq4[k4 * 1536 + 512 + j];
                v4 wn = wq4[k4 * 1536 + 1024 + j];
                ar += dot4(hv, wr); az += dot4(hv, wz); an += dot4(hv, wn);
            }
            float gir = EgiT[j * 32 + id];
            float giz = EgiT[(512 + j) * 32 + id];
            float gin = EgiT[(1024 + j) * 32 + id];
            float sr = ar + b_hh[j] + gir;
            float sz = az + b_hh[512 + j] + giz;
            float sn = an + b_hh[1024 + j];
            float r = 1.f / (1.f + __expf(-sr));
            float z = 1.f / (1.f + __expf(-sz));
            float n = tanhf(gin + r * sn);
            float hold = s_h[((j >> 2) * 32 + bg) * 4 + (j & 3)];
            pushf(hPx + ((j >> 2) * 32 + bg) * 4 + (j & 3), (1.f - z) * n + z * hold);
        }
        grid_barrier(bar, ep++);

        // ================= P2: attention (one block per batch row b2) =================
        {
            const int b2 = x * 32 + m;
            {
                float hv_ = pullf(hPx + ((tid >> 2) * 32 + m) * 4 + (tid & 3));
                wait_pull();
                s_hrow[tid] = hv_;
            }
            __syncthreads();
            const v4* sr4 = (const v4*)s_hrow;
            {
                float a = 0.f;
#pragma unroll 4
                for (int i = 0; i < 16; ++i) {
                    int k4 = w * 16 + i;
                    a += dot4(sr4[k4], wm4[k4 * 64 + lane]);
                }
                s_part[w][lane] = a;
            }
            __syncthreads();
            if (w == 0) {
                float a = s_part[0][lane];
                for (int i = 1; i < 8; ++i) a += s_part[i][lane];
                s_hp[lane] = a;
            }
            __syncthreads();

            const int u0 = (lane & 7) * 8;
            const int tsub = lane >> 3;
            v4 hpA = *(const v4*)&s_hp[u0];
            v4 hpB = *(const v4*)&s_hp[u0 + 4];
            float mx = -1e30f, S = 0.f;
            float cx[8] = {0.f, 0.f, 0.f, 0.f, 0.f, 0.f, 0.f, 0.f};
#pragma unroll
            for (int p = 0; p < 8; ++p) {
                int tt = p * 64 + w * 8 + tsub;
                v4 ua = {0.f, 0.f, 0.f, 0.f}, ub = {0.f, 0.f, 0.f, 0.f};
                float part = 0.f;
                if (tt < TS) {
                    const v4* ur = (const v4*)(up + ((size_t)b2 * TS + tt) * UPS + u0);
                    ua = ur[0];
                    ub = ur[1];
                    part = dot4(ua, hpA) + dot4(ub, hpB);
                }
                part += __shfl_xor(part, 1);
                part += __shfl_xor(part, 2);
                part += __shfl_xor(part, 4);
                float s = (tt < TS) ? part : -1e30f;
                float M = s;
                M = fmaxf(M, __shfl_xor(M, 8));
                M = fmaxf(M, __shfl_xor(M, 16));
                M = fmaxf(M, __shfl_xor(M, 32));
                float mn = fmaxf(mx, M);
                float alpha = __expf(mx - mn);
                float e = __expf(s - mn);
                float E = e;
                E += __shfl_xor(E, 8); E += __shfl_xor(E, 16); E += __shfl_xor(E, 32);
                S = S * alpha + E;
                mx = mn;
#pragma unroll
                for (int i = 0; i < 4; ++i) cx[i] = cx[i] * alpha + e * ua[i];
#pragma unroll
                for (int i = 0; i < 4; ++i) cx[4 + i] = cx[4 + i] * alpha + e * ub[i];
            }
#pragma unroll
            for (int i = 0; i < 8; ++i) {
                cx[i] += __shfl_xor(cx[i], 8);
                cx[i] += __shfl_xor(cx[i], 16);
                cx[i] += __shfl_xor(cx[i], 32);
            }
            if (tsub == 0) {
#pragma unroll
                for (int i = 0; i < 8; ++i) s_ctx[w][u0 + i] = cx[i];
            }
            if (lane == 0) { s_mw[w] = mx; s_Sw[w] = S; }
            __syncthreads();
            if (tid < UPS) {
                float M = s_mw[0];
                for (int i = 1; i < 8; ++i) M = fmaxf(M, s_mw[i]);
                float Sg = 0.f, c = 0.f;
                for (int i = 0; i < 8; ++i) {
                    float f = __expf(s_mw[i] - M);
                    Sg += s_Sw[i] * f;
                    c += s_ctx[i][tid] * f;
                }
                pushf(uctxX + m * 64 + tid, c / Sg);
            }
        }
        grid_barrier(bar, ep++);

        // ================= P3: concat GEMM + logits partials =================
        {
            // bulk-stage h_new (reused by next step's P1) + uctx
            v4 tmp[8];
#pragma unroll
            for (int i = 0; i < 8; ++i) tmp[i] = pull4(hPx + (i * 512 + tid) * 4);
            float ut[4];
#pragma unroll
            for (int i = 0; i < 4; ++i) ut[i] = pullf(uctxX + i * 512 + tid);
            wait_pull();
            v4* sh4w = (v4*)s_h;
#pragma unroll
            for (int i = 0; i < 8; ++i) sh4w[i * 512 + tid] = tmp[i];
#pragma unroll
            for (int i = 0; i < 4; ++i) {
                int idx = i * 512 + tid;
                s_uctx[(idx >> 6) * 68 + (idx & 63)] = ut[i];
            }
        }
        __syncthreads();
        {
            float acc = 0.f;
#pragma unroll 4
            for (int k4 = 0; k4 < 128; ++k4) {
                v4 hv = sh4[k4 * 32 + bg];
                v4 wv = wc4[k4 * 512 + j];
                acc += dot4(hv, wv);
            }
            const v4* su4 = (const v4*)s_uctx;
#pragma unroll
            for (int u4 = 0; u4 < 16; ++u4) {
                v4 uv = su4[bg * 17 + u4];
                v4 wv = wf4[u4 * 512 + j];
                acc += dot4(uv, wv);
            }
            float c = tanhf(acc + bcat2[j]);
#pragma unroll
            for (int v = 0; v < V; ++v) {
                float p = c * W_out[(size_t)v * H + j];
                p += __shfl_xor(p, 1);
                p += __shfl_xor(p, 2);
                p += __shfl_xor(p, 4);
                p += __shfl_xor(p, 8);
                if (jg == 0) s_lgp[v * 32 + bg] = p;
            }
        }
        __syncthreads();
#pragma unroll
        for (int i = 0; i < 2; ++i) {
            int idx = tid + i * 512;
            if (idx < 800) pushf(lgP + (size_t)bid * 800 + idx, s_lgp[idx]);
        }
        grid_barrier(bar, ep++);

        // ================= P4: logits reduction + argmax source + out write =================
        if (m < V) {
            const int bgl = tid & 31, mh = tid >> 5;  // mh in [0,16)
            float s0 = pullf(lgP + (size_t)(mh * 8 + x) * 800 + m * 32 + bgl);
            float s1 = pullf(lgP + (size_t)((mh + 16) * 8 + x) * 800 + m * 32 + bgl);
            wait_pull();
            s_red[mh][bgl] = s0 + s1;
            __syncthreads();
            if (tid < 32) {
                float sum = b_out[m];
#pragma unroll
                for (int i = 0; i < 16; ++i) sum += s_red[i][tid];
                pushf(lgF + x * 800 + m * 32 + tid, sum);
                out[((size_t)(x * 32 + tid) * V + m) * TS + t] = sum;
            }
        }
        grid_barrier(bar, ep++);
    }
}

// ---------------- launcher ----------------

extern "C" void kernel_launch(void* const* d_in, const int* in_sizes, int n_in,
                              void* d_out, int out_size, void* d_ws, size_t ws_size,
                              hipStream_t stream) {
    const float* latent = (const float*)d_in[0];
    const float* up     = (const float*)d_in[1];
    const float* embed  = (const float*)d_in[2];
    const float* W_hid  = (const float*)d_in[3];
    const float* b_hid  = (const float*)d_in[4];
    const float* W_ih   = (const float*)d_in[5];
    const float* b_ih   = (const float*)d_in[6];
    const float* W_hh   = (const float*)d_in[7];
    const float* b_hh   = (const float*)d_in[8];
    const float* W_mem  = (const float*)d_in[9];
    const float* b_mem  = (const float*)d_in[10];
    const float* W_cat  = (const float*)d_in[11];
    const float* b_cat  = (const float*)d_in[12];
    const float* W_out  = (const float*)d_in[13];
    const float* b_out  = (const float*)d_in[14];
    float* out = (float*)d_out;
    float* ws = (float*)d_ws;

    k_init_egi<<<(V * 3 * H + 255) / 256, 256, 0, stream>>>(embed, W_ih, b_ih, ws + OFF_EGI);
    k_init_h0<<<NB, H, 0, stream>>>(latent, W_hid, b_hid, ws + OFF_HP);
    k_pack_whh<<<(1536 * 128 + 255) / 256, 256, 0, stream>>>(W_hh, ws + OFF_WHHQ);
    k_pack_wcat<<<(512 * 128 + 255) / 256, 256, 0, stream>>>(W_cat, ws + OFF_WCATQ);
    k_init_fold<<<(H * UPS + 255) / 256, 256, 0, stream>>>(W_cat, W_mem, ws + OFF_WFOLDQ);
    k_init_bcat<<<(H + 255) / 256, 256, 0, stream>>>(W_cat, b_mem, b_cat, ws + OFF_BCAT2);
    k_pack_wmem<<<(128 * 64 + 255) / 256, 256, 0, stream>>>(W_mem, ws + OFF_WMQ);
    k_init_bar<<<1, 1024, 0, stream>>>((int*)(ws + OFF_BAR));

    k_main<<<NBLK, 512, 0, stream>>>(up, b_hh, W_out, b_out, out, ws);
}

// Round 6
// 21169.455 us; speedup vs baseline: 4.2169x; 2.6701x over previous
//
#include <hip/hip_runtime.h>
#include <math.h>

typedef float v4 __attribute__((ext_vector_type(4)));

#define NB 256
#define LATD 128
#define UPS 64
#define H 512
#define V 25
#define TS 500
#define NBLK 256
#define NGRP 16
#define GSZ (NBLK / NGRP)

// ---- float offsets in workspace ----
#define OFF_HP     0                         // hP[256][512]
#define OFF_UCTX   131072                    // uctx[256][64]
#define OFF_LGP    147456                    // lgp[8][256][25]
#define OFF_EGI    198656                    // Egi2[25][1536]
#define OFF_WHHQ   237056                    // Whh_q[128][1536][4]
#define OFF_WCATQ  1023488                   // Wcat_q[128][512][4]
#define OFF_WFOLDQ 1285632                   // Wfold_q[16][512][4]
#define OFF_WMQ    1318400                   // Wm_q2[128][64][4]
#define OFF_BCAT2  1351168                   // bcat2[512]
#define OFF_BAR    1351680                   // barrier ints

__device__ __forceinline__ float dot4(v4 a, v4 b) {
    return a.x * b.x + a.y * b.y + a.z * b.z + a.w * b.w;
}

// ---- MALL-coherent bulk access helpers (proven in r5) ----
__device__ __forceinline__ float pullf(const float* p) {
    float r;
    asm volatile("global_load_dword %0, %1, off sc0 sc1" : "=v"(r) : "v"(p));
    return r;
}
__device__ __forceinline__ v4 pull4(const float* p) {
    v4 r;
    asm volatile("global_load_dwordx4 %0, %1, off sc0 sc1" : "=v"(r) : "v"(p));
    return r;
}
__device__ __forceinline__ void pushf(float* p, float x) {
    asm volatile("global_store_dword %0, %1, off sc0 sc1" :: "v"(p), "v"(x));
}
__device__ __forceinline__ void wait_pull() {
    asm volatile("s_waitcnt vmcnt(0)" ::: "memory");
    __builtin_amdgcn_sched_barrier(0);
}

// ---------------- init kernels ----------------

__global__ void k_init_egi(const float* __restrict__ embed, const float* __restrict__ W_ih,
                           const float* __restrict__ b_ih, float* __restrict__ Egi2) {
    int idx = blockIdx.x * 256 + threadIdx.x;
    if (idx >= V * 3 * H) return;
    int v = idx % V, n = idx / V;
    const float* e = embed + (size_t)v * H;
    const float* wr = W_ih + (size_t)n * H;
    float acc = b_ih[n];
    for (int k = 0; k < H; ++k) acc += e[k] * wr[k];
    Egi2[(size_t)v * 1536 + n] = acc;
}

__global__ void k_init_h0(const float* __restrict__ latent, const float* __restrict__ W_hid,
                          const float* __restrict__ b_hid, float* __restrict__ hP) {
    int b = blockIdx.x, j = threadIdx.x;
    const float* l = latent + (size_t)b * LATD;
    const float* wr = W_hid + (size_t)j * LATD;
    float acc = b_hid[j];
    for (int k = 0; k < LATD; ++k) acc += l[k] * wr[k];
    hP[(size_t)b * H + j] = acc;
}

__global__ void k_pack_whh(const float* __restrict__ W_hh, float* __restrict__ Whh_q) {
    int idx = blockIdx.x * 256 + threadIdx.x;
    if (idx >= 1536 * 128) return;
    int k4 = idx & 127, row = idx >> 7;
    v4 val = *(const v4*)(W_hh + (size_t)row * H + k4 * 4);
    *(v4*)(Whh_q + ((size_t)k4 * 1536 + row) * 4) = val;
}

__global__ void k_pack_wcat(const float* __restrict__ W_cat, float* __restrict__ Wcat_q) {
    int idx = blockIdx.x * 256 + threadIdx.x;
    if (idx >= 512 * 128) return;
    int k4 = idx & 127, row = idx >> 7;
    v4 val = *(const v4*)(W_cat + (size_t)row * (2 * H) + k4 * 4);
    *(v4*)(Wcat_q + ((size_t)k4 * 512 + row) * 4) = val;
}

__global__ void k_init_fold(const float* __restrict__ W_cat, const float* __restrict__ W_mem,
                            float* __restrict__ Wfold_q) {
    int idx = blockIdx.x * 256 + threadIdx.x;
    if (idx >= H * UPS) return;
    int u = idx & 63, j = idx >> 6;
    float acc = 0.f;
    for (int k = 0; k < H; ++k)
        acc += W_cat[(size_t)j * (2 * H) + H + k] * W_mem[(size_t)k * UPS + u];
    Wfold_q[((u >> 2) * 512 + j) * 4 + (u & 3)] = acc;
}

__global__ void k_init_bcat(const float* __restrict__ W_cat, const float* __restrict__ b_mem,
                            const float* __restrict__ b_cat, float* __restrict__ bcat2) {
    int j = blockIdx.x * 256 + threadIdx.x;
    if (j >= H) return;
    float acc = b_cat[j];
    for (int k = 0; k < H; ++k) acc += W_cat[(size_t)j * (2 * H) + H + k] * b_mem[k];
    bcat2[j] = acc;
}

__global__ void k_pack_wmem(const float* __restrict__ W_mem, float* __restrict__ Wm_q2) {
    int idx = blockIdx.x * 256 + threadIdx.x;
    if (idx >= 128 * 64) return;
    int u = idx & 63, k4 = idx >> 6;
    v4 val;
    val.x = W_mem[(size_t)(k4 * 4 + 0) * UPS + u];
    val.y = W_mem[(size_t)(k4 * 4 + 1) * UPS + u];
    val.z = W_mem[(size_t)(k4 * 4 + 2) * UPS + u];
    val.w = W_mem[(size_t)(k4 * 4 + 3) * UPS + u];
    *(v4*)(Wm_q2 + ((size_t)k4 * 64 + u) * 4) = val;
}

__global__ void k_init_bar(int* __restrict__ bar) {
    int i = threadIdx.x;
    if (i < NGRP * 32 + 64) bar[i] = 0;
}

// ---------------- grid barrier (r4/r5 proven semantics) ----------------

__device__ __forceinline__ void grid_barrier(int* bar, int epoch) {
    asm volatile("s_waitcnt vmcnt(0)" ::: "memory");  // drain asm pushes of this wave
    __syncthreads();
    asm volatile("" ::: "memory");
    if (threadIdx.x == 0) {
        int* gcnt = bar + (blockIdx.x & (NGRP - 1)) * 32;
        int* root = bar + NGRP * 32;
        int* gen  = bar + NGRP * 32 + 32;
        int a = __hip_atomic_fetch_add(gcnt, 1, __ATOMIC_RELEASE, __HIP_MEMORY_SCOPE_AGENT);
        if (a == epoch * GSZ + (GSZ - 1)) {
            int r = __hip_atomic_fetch_add(root, 1, __ATOMIC_RELEASE, __HIP_MEMORY_SCOPE_AGENT);
            if (r == epoch * NGRP + (NGRP - 1))
                __hip_atomic_store(gen, epoch + 1, __ATOMIC_RELEASE, __HIP_MEMORY_SCOPE_AGENT);
        }
        while (__hip_atomic_load(gen, __ATOMIC_RELAXED, __HIP_MEMORY_SCOPE_AGENT) <= epoch)
            __builtin_amdgcn_s_sleep(1);
    }
    asm volatile("" ::: "memory");
    __syncthreads();
}

// ---------------- persistent main kernel ----------------

__global__ __launch_bounds__(512, 1) void k_main(
    const float* __restrict__ up, const float* __restrict__ b_hh,
    const float* __restrict__ W_out, const float* __restrict__ b_out,
    float* __restrict__ out, float* __restrict__ ws)
{
    float* hP    = ws + OFF_HP;
    float* uctxB = ws + OFF_UCTX;
    float* lgp   = ws + OFF_LGP;
    const float* Egi2    = ws + OFF_EGI;
    const float* Whh_q   = ws + OFF_WHHQ;
    const float* Wcat_q  = ws + OFF_WCATQ;
    const float* Wfold_q = ws + OFF_WFOLDQ;
    const float* Wm_q2   = ws + OFF_WMQ;
    const float* bcat2   = ws + OFF_BCAT2;
    int*   bar   = (int*)(ws + OFF_BAR);

    const int tid = threadIdx.x;
    const int bid = blockIdx.x;
    const int jx = bid & 7;          // j-slice (pinned per XCD): j = jx*64 + jg
    const int bs = bid >> 3;         // batch slice: rows bs*8 .. bs*8+7
    const int jg = tid & 63;         // j within slice (GEMM phases)
    const int wk = tid >> 6;         // k-split wave (GEMM phases)
    const int j = jx * 64 + jg;
    const int w = tid >> 6, lane = tid & 63;   // P2 naming
    const int b2 = jx * 32 + bs;               // P2 batch row (pinned per XCD)

    const v4* wq4 = (const v4*)Whh_q;
    const v4* wc4 = (const v4*)Wcat_q;
    const v4* wf4 = (const v4*)Wfold_q;
    const v4* wm4 = (const v4*)Wm_q2;

    __shared__ __align__(16) float s_h[128 * 9 * 4];     // h[k4][bl(9-pad)][4]
    __shared__ float s_red[8 * 64 * 25];                 // partials [wk][jg][25-pad]
    __shared__ __align__(16) float s_uctx[16 * 8 * 4];   // uctx[u4][bl][4]
    __shared__ float s_c[64 * 9];                        // concat [jg][bl(9-pad)]
    __shared__ float s_lg[8 * 26];                       // summed logits [bl][26-pad]
    __shared__ int   s_id[8];
    __shared__ __align__(16) float s_hrow[512];          // P2: h row
    __shared__ float s_part[8][64];
    __shared__ __align__(16) float s_hp[64];
    __shared__ float s_ctx[8][64];
    __shared__ float s_mw[8], s_Sw[8];

    v4* s_h4 = (v4*)s_h;
    const v4* s_u4 = (const v4*)s_uctx;

    int ep = 0;

    // ---- prologue: stage h0 rows (bs*8..+8) into LDS ----
    {
        const int k4s = tid >> 2, blp = (tid & 3) * 2;
        v4 aa = pull4(hP + (size_t)(bs * 8 + blp) * H + k4s * 4);
        v4 bb = pull4(hP + (size_t)(bs * 8 + blp + 1) * H + k4s * 4);
        wait_pull();
        s_h4[k4s * 9 + blp] = aa;
        s_h4[k4s * 9 + blp + 1] = bb;
    }
    grid_barrier(bar, ep++);

    for (int t = 0; t < TS; ++t) {
        // ================= P1: logits reduce + argmax + GRU =================
        if (t > 0) {
            if (tid < 200) {
                const int bl = tid / 25, v = tid - bl * 25;
                const int b = bs * 8 + bl;
                float p0 = pullf(lgp + ((size_t)0 * 256 + b) * 25 + v);
                float p1 = pullf(lgp + ((size_t)1 * 256 + b) * 25 + v);
                float p2 = pullf(lgp + ((size_t)2 * 256 + b) * 25 + v);
                float p3 = pullf(lgp + ((size_t)3 * 256 + b) * 25 + v);
                float p4 = pullf(lgp + ((size_t)4 * 256 + b) * 25 + v);
                float p5 = pullf(lgp + ((size_t)5 * 256 + b) * 25 + v);
                float p6 = pullf(lgp + ((size_t)6 * 256 + b) * 25 + v);
                float p7 = pullf(lgp + ((size_t)7 * 256 + b) * 25 + v);
                wait_pull();
                float s = ((p0 + p1) + (p2 + p3)) + ((p4 + p5) + (p6 + p7)) + b_out[v];
                s_lg[bl * 26 + v] = s;
                if (jx == 0) out[((size_t)b * V + v) * TS + (t - 1)] = s;
            }
            __syncthreads();
            if (tid < 8) {
                float best = s_lg[tid * 26];
                int bi = 0;
                for (int v = 1; v < V; ++v) {
                    float x = s_lg[tid * 26 + v];
                    if (x > best) { best = x; bi = v; }
                }
                s_id[tid] = bi;
            }
            __syncthreads();
        } else {
            if (tid < 8) s_id[tid] = 0;   // SOS
            __syncthreads();
        }
        // GRU GEMM: wave wk handles k4 in [wk*16, wk*16+16), 8 b in registers
        {
            float a0[8], a1[8], a2[8];
#pragma unroll
            for (int bl = 0; bl < 8; ++bl) { a0[bl] = 0.f; a1[bl] = 0.f; a2[bl] = 0.f; }
            const int kbase = wk * 16;
#pragma unroll 4
            for (int kk = 0; kk < 16; ++kk) {
                const int k4 = kbase + kk;
                const v4 wr = wq4[k4 * 1536 + j];
                const v4 wz = wq4[k4 * 1536 + 512 + j];
                const v4 wn = wq4[k4 * 1536 + 1024 + j];
                const v4* hrow = &s_h4[k4 * 9];
#pragma unroll
                for (int bl = 0; bl < 8; ++bl) {
                    v4 hv = hrow[bl];
                    a0[bl] += dot4(hv, wr);
                    a1[bl] += dot4(hv, wz);
                    a2[bl] += dot4(hv, wn);
                }
            }
            const int rb = wk * 1600 + jg * 25;
#pragma unroll
            for (int bl = 0; bl < 8; ++bl) {
                s_red[rb + bl] = a0[bl];
                s_red[rb + 8 + bl] = a1[bl];
                s_red[rb + 16 + bl] = a2[bl];
            }
        }
        __syncthreads();
        // gate math: thread (bl = tid>>6, jg2 = tid&63)
        {
            const int bl = tid >> 6, jg2 = tid & 63;
            const int j2 = jx * 64 + jg2;
            float sr = 0.f, sz = 0.f, sn = 0.f;
#pragma unroll
            for (int wk2 = 0; wk2 < 8; ++wk2) {
                const int base = wk2 * 1600 + jg2 * 25;
                sr += s_red[base + bl];
                sz += s_red[base + 8 + bl];
                sn += s_red[base + 16 + bl];
            }
            const int id = s_id[bl];
            const float gir = Egi2[(size_t)id * 1536 + j2];
            const float giz = Egi2[(size_t)id * 1536 + 512 + j2];
            const float gin = Egi2[(size_t)id * 1536 + 1024 + j2];
            sr += b_hh[j2] + gir;
            sz += b_hh[512 + j2] + giz;
            sn += b_hh[1024 + j2];
            const float r = 1.f / (1.f + __expf(-sr));
            const float z = 1.f / (1.f + __expf(-sz));
            const float n = tanhf(gin + r * sn);
            const float hold = s_h[((j2 >> 2) * 9 + bl) * 4 + (j2 & 3)];
            pushf(hP + (size_t)(bs * 8 + bl) * H + j2, (1.f - z) * n + z * hold);
        }
        grid_barrier(bar, ep++);

        // ================= P2: attention (one block per row b2) =================
        {
            float hv_ = pullf(hP + (size_t)b2 * H + tid);
            wait_pull();
            s_hrow[tid] = hv_;
            __syncthreads();
            const v4* sr4 = (const v4*)s_hrow;
            {
                float a = 0.f;
#pragma unroll 4
                for (int i = 0; i < 16; ++i) {
                    const int k4 = w * 16 + i;
                    a += dot4(sr4[k4], wm4[k4 * 64 + lane]);
                }
                s_part[w][lane] = a;
            }
            __syncthreads();
            if (w == 0) {
                float a = s_part[0][lane];
                for (int i = 1; i < 8; ++i) a += s_part[i][lane];
                s_hp[lane] = a;
            }
            __syncthreads();

            const int u0 = (lane & 7) * 8;
            const int tsub = lane >> 3;
            v4 hpA = *(const v4*)&s_hp[u0];
            v4 hpB = *(const v4*)&s_hp[u0 + 4];
            float mx = -1e30f, S = 0.f;
            float cx[8] = {0.f, 0.f, 0.f, 0.f, 0.f, 0.f, 0.f, 0.f};
#pragma unroll
            for (int p = 0; p < 8; ++p) {
                const int tt = p * 64 + w * 8 + tsub;
                v4 ua = {0.f, 0.f, 0.f, 0.f}, ub = {0.f, 0.f, 0.f, 0.f};
                float part = 0.f;
                if (tt < TS) {
                    const v4* ur = (const v4*)(up + ((size_t)b2 * TS + tt) * UPS + u0);
                    ua = ur[0];
                    ub = ur[1];
                    part = dot4(ua, hpA) + dot4(ub, hpB);
                }
                part += __shfl_xor(part, 1);
                part += __shfl_xor(part, 2);
                part += __shfl_xor(part, 4);
                const float s = (tt < TS) ? part : -1e30f;
                float M = s;
                M = fmaxf(M, __shfl_xor(M, 8));
                M = fmaxf(M, __shfl_xor(M, 16));
                M = fmaxf(M, __shfl_xor(M, 32));
                const float mn = fmaxf(mx, M);
                const float alpha = __expf(mx - mn);
                const float e = __expf(s - mn);
                float E = e;
                E += __shfl_xor(E, 8); E += __shfl_xor(E, 16); E += __shfl_xor(E, 32);
                S = S * alpha + E;
                mx = mn;
#pragma unroll
                for (int i = 0; i < 4; ++i) cx[i] = cx[i] * alpha + e * ua[i];
#pragma unroll
                for (int i = 0; i < 4; ++i) cx[4 + i] = cx[4 + i] * alpha + e * ub[i];
            }
#pragma unroll
            for (int i = 0; i < 8; ++i) {
                cx[i] += __shfl_xor(cx[i], 8);
                cx[i] += __shfl_xor(cx[i], 16);
                cx[i] += __shfl_xor(cx[i], 32);
            }
            if (tsub == 0) {
#pragma unroll
                for (int i = 0; i < 8; ++i) s_ctx[w][u0 + i] = cx[i];
            }
            if (lane == 0) { s_mw[w] = mx; s_Sw[w] = S; }
            __syncthreads();
            if (tid < UPS) {
                float M = s_mw[0];
                for (int i = 1; i < 8; ++i) M = fmaxf(M, s_mw[i]);
                float Sg = 0.f, c = 0.f;
                for (int i = 0; i < 8; ++i) {
                    const float f = __expf(s_mw[i] - M);
                    Sg += s_Sw[i] * f;
                    c += s_ctx[i][tid] * f;
                }
                pushf(uctxB + (size_t)b2 * UPS + tid, c / Sg);
            }
        }
        grid_barrier(bar, ep++);

        // ================= P3: stage h_new+uctx, concat GEMM, logits partials =================
        {
            const int k4s = tid >> 2, blp = (tid & 3) * 2;
            v4 aa = pull4(hP + (size_t)(bs * 8 + blp) * H + k4s * 4);
            v4 bb = pull4(hP + (size_t)(bs * 8 + blp + 1) * H + k4s * 4);
            const int uu = tid & 63, blu = tid >> 6;
            float uv = pullf(uctxB + (size_t)(bs * 8 + blu) * UPS + uu);
            wait_pull();
            s_h4[k4s * 9 + blp] = aa;
            s_h4[k4s * 9 + blp + 1] = bb;
            s_uctx[((uu >> 2) * 8 + blu) * 4 + (uu & 3)] = uv;
        }
        __syncthreads();
        {
            float acc[8];
#pragma unroll
            for (int bl = 0; bl < 8; ++bl) acc[bl] = 0.f;
            const int kbase = wk * 16;
#pragma unroll 4
            for (int kk = 0; kk < 16; ++kk) {
                const int k4 = kbase + kk;
                const v4 wv = wc4[k4 * 512 + j];
                const v4* hrow = &s_h4[k4 * 9];
#pragma unroll
                for (int bl = 0; bl < 8; ++bl) acc[bl] += dot4(hrow[bl], wv);
            }
#pragma unroll
            for (int ui = 0; ui < 2; ++ui) {
                const int u4 = wk * 2 + ui;
                const v4 wv = wf4[u4 * 512 + j];
#pragma unroll
                for (int bl = 0; bl < 8; ++bl) acc[bl] += dot4(s_u4[u4 * 8 + bl], wv);
            }
            const int rb = wk * 1600 + jg * 25;
#pragma unroll
            for (int bl = 0; bl < 8; ++bl) s_red[rb + bl] = acc[bl];
        }
        __syncthreads();
        {
            const int bl = tid >> 6, jg2 = tid & 63;
            const int j2 = jx * 64 + jg2;
            float a = 0.f;
#pragma unroll
            for (int wk2 = 0; wk2 < 8; ++wk2) a += s_red[wk2 * 1600 + jg2 * 25 + bl];
            s_c[jg2 * 9 + bl] = tanhf(a + bcat2[j2]);
        }
        __syncthreads();
        if (tid < 200) {
            const int bl = tid / 25, v = tid - bl * 25;
            float a = 0.f;
            const float* wo = W_out + (size_t)v * H + jx * 64;
#pragma unroll 8
            for (int jj = 0; jj < 64; ++jj) a += s_c[jj * 9 + bl] * wo[jj];
            pushf(lgp + ((size_t)jx * 256 + (bs * 8 + bl)) * 25 + v, a);
        }
        grid_barrier(bar, ep++);
    }

    // ---- tail: final logits (t = TS-1) ----
    if (jx == 0 && tid < 200) {
        const int bl = tid / 25, v = tid - bl * 25;
        const int b = bs * 8 + bl;
        float s = b_out[v];
#pragma unroll
        for (int x2 = 0; x2 < 8; ++x2) s += pullf(lgp + ((size_t)x2 * 256 + b) * 25 + v);
        wait_pull();
        out[((size_t)b * V + v) * TS + (TS - 1)] = s;
    }
}

// ---------------- launcher ----------------

extern "C" void kernel_launch(void* const* d_in, const int* in_sizes, int n_in,
                              void* d_out, int out_size, void* d_ws, size_t ws_size,
                              hipStream_t stream) {
    const float* latent = (const float*)d_in[0];
    const float* up     = (const float*)d_in[1];
    const float* embed  = (const float*)d_in[2];
    const float* W_hid  = (const float*)d_in[3];
    const float* b_hid  = (const float*)d_in[4];
    const float* W_ih   = (const float*)d_in[5];
    const float* b_ih   = (const float*)d_in[6];
    const float* W_hh   = (const float*)d_in[7];
    const float* b_hh   = (const float*)d_in[8];
    const float* W_mem  = (const float*)d_in[9];
    const float* b_mem  = (const float*)d_in[10];
    const float* W_cat  = (const float*)d_in[11];
    const float* b_cat  = (const float*)d_in[12];
    const float* W_out  = (const float*)d_in[13];
    const float* b_out  = (const float*)d_in[14];
    float* out = (float*)d_out;
    float* ws = (float*)d_ws;

    k_init_egi<<<(V * 3 * H + 255) / 256, 256, 0, stream>>>(embed, W_ih, b_ih, ws + OFF_EGI);
    k_init_h0<<<NB, H, 0, stream>>>(latent, W_hid, b_hid, ws + OFF_HP);
    k_pack_whh<<<(1536 * 128 + 255) / 256, 256, 0, stream>>>(W_hh, ws + OFF_WHHQ);
    k_pack_wcat<<<(512 * 128 + 255) / 256, 256, 0, stream>>>(W_cat, ws + OFF_WCATQ);
    k_init_fold<<<(H * UPS + 255) / 256, 256, 0, stream>>>(W_cat, W_mem, ws + OFF_WFOLDQ);
    k_init_bcat<<<(H + 255) / 256, 256, 0, stream>>>(W_cat, b_mem, b_cat, ws + OFF_BCAT2);
    k_pack_wmem<<<(128 * 64 + 255) / 256, 256, 0, stream>>>(W_mem, ws + OFF_WMQ);
    k_init_bar<<<1, 1024, 0, stream>>>((int*)(ws + OFF_BAR));

    k_main<<<NBLK, 512, 0, stream>>>(up, b_hh, W_out, b_out, out, ws);
}